// Round 7
// baseline (141.784 us; speedup 1.0000x reference)
//
#include <hip/hip_runtime.h>
#include <cstdint>

#define B_ 16
#define N_ 2048
#define D_ 256
#define EPS_ 1e-9f

#define AS1 __attribute__((address_space(1)))
#define AS3 __attribute__((address_space(3)))

typedef float f4 __attribute__((ext_vector_type(4)));
typedef float f16v __attribute__((ext_vector_type(16)));
typedef int v8i __attribute__((ext_vector_type(8)));

__device__ float blockReduceSum(float x, float* red){
  int tid = threadIdx.x;
  red[tid] = x; __syncthreads();
  #pragma unroll
  for (int off = 128; off > 0; off >>= 1){
    if (tid < off) red[tid] += red[tid + off];
    __syncthreads();
  }
  float r = red[0]; __syncthreads();
  return r;
}

// fp32 norm + fp8(e4m3) conversion; 4 rows/wave, 16 rows/block (one batch/block).
// Emits race-free per-block partials Ppart/npart for tail's fast path.
// Also inits cost/currency/dmin/out (no separate memset dispatch).
__global__ __launch_bounds__(256) void prep_kernel(
    const float* __restrict__ preds, const float* __restrict__ labels,
    unsigned char* __restrict__ pa8, unsigned char* __restrict__ pb8,
    float* __restrict__ pn, float* __restrict__ ln,
    float* __restrict__ cost, float* __restrict__ currency,
    int* __restrict__ dmin, float* __restrict__ Ppart,
    float* __restrict__ npart, float* __restrict__ out){
  int s = blockIdx.y;
  int tid = threadIdx.x;
  if (s == 0){
    int i = blockIdx.x * 256 + tid;
    if (i < B_ * N_){ cost[i] = 1.f; currency[i] = 1.f; }
    if (i < B_) dmin[i] = 0x7f7fffff;  // FLT_MAX bits
    if (i == 0) out[0] = 0.f;
  }
  const float* src = s ? labels : preds;
  unsigned char* dst = s ? pb8 : pa8;
  float* norms = s ? ln : pn;
  int w = tid >> 6, lane = tid & 63;
  size_t row0 = (size_t)blockIdx.x * 16 + (size_t)w * 4;
  float4 v[4];
  #pragma unroll
  for (int q = 0; q < 4; q++)
    v[q] = ((const float4*)(src + (row0 + q) * D_))[lane];
  __shared__ f4 part[4][64];
  __shared__ float nred[4];
  f4 s4;
  s4[0] = v[0].x + v[1].x + v[2].x + v[3].x;
  s4[1] = v[0].y + v[1].y + v[2].y + v[3].y;
  s4[2] = v[0].z + v[1].z + v[2].z + v[3].z;
  s4[3] = v[0].w + v[1].w + v[2].w + v[3].w;
  float nsum = 0.f;
  #pragma unroll
  for (int q = 0; q < 4; q++){
    float sum = v[q].x*v[q].x + v[q].y*v[q].y + v[q].z*v[q].z + v[q].w*v[q].w;
    #pragma unroll
    for (int off = 32; off >= 1; off >>= 1) sum += __shfl_xor(sum, off);
    if (lane == 0){ norms[row0 + q] = sum; nsum += sum; }
    int pk = 0;
    pk = __builtin_amdgcn_cvt_pk_fp8_f32(v[q].x, v[q].y, pk, false); // bytes 0,1
    pk = __builtin_amdgcn_cvt_pk_fp8_f32(v[q].z, v[q].w, pk, true);  // bytes 2,3
    ((unsigned int*)(dst + (row0 + q) * D_))[lane] = (unsigned int)pk;
  }
  part[w][lane] = s4;
  if (lane == 0) nred[w] = nsum;
  __syncthreads();
  if (tid < 64){
    f4 t = part[0][tid];
    #pragma unroll
    for (int q = 1; q < 4; q++){
      t[0] += part[q][tid][0]; t[1] += part[q][tid][1];
      t[2] += part[q][tid][2]; t[3] += part[q][tid][3];
    }
    *(f4*)(Ppart + ((size_t)s * 2048 + blockIdx.x) * 256 + tid * 4) = t;
  }
  if (tid == 0)
    npart[s * 2048 + blockIdx.x] = nred[0] + nred[1] + nred[2] + nred[3];
}

// d[b][n][m] = pn[n] + ln[m] - 2*dot via MX-SCALED FP8 MFMA; NO stores — only
// per-batch min. Round-17 resubmit (R6 bench was an infra failure: container
// acquisition failed twice; kernel re-audited — LDS-union WAR/RAW race-free
// under __syncthreads' vmcnt+lgkm drain, pn staging in-bounds, all gload_lds
// dests wave-uniform+lane*size). OCCUPANCY fix: R4/R5 showed gemm's non-MFMA
// residual (~16us) is additive-serial overhead at 1 block/CU (lockstep
// barriers, LDS storms, epilogue latency; 2 waves/SIMD, nothing to overlap
// with). Fix: 2 independent blocks/CU. (1) LDS union — after the one-time bfr
// register cache is filled, Bs is DEAD: reuse its 64 KB as the As dbuf ->
// LDS 128 -> 64 KB/block. (2) VGPR <= 128 (the m69 cliff): wave tile 32x64
// (acc 1x2xf32x16 = 32 VGPR, bfr 64, af 8 transient), __launch_bounds__(512,4).
// (3) pn staged into the freed LDS (2 KB, broadcast ds_reads) — kills the
// per-step L2 latency in the epilogue. Grid 512 = 8 tn-panels x 4 tm-quarters
// x 16 batches; 8 stripes of 64 rows, full-K each. A redundancy unchanged
// (8x); B staged 2x more (+16 MB, paid in overlappable prologues). All proven
// geometry verbatim: global-side XOR r&7 16-B-chunk swizzle, gload_lds
// wave-base staging, 32x32x64 fragments, C/D col=lane&31,
// row=(reg&3)+8*(reg>>2)+4*(lane>>5). With 4 waves/SIMD from 2 blocks, one
// block's drains hide under the other's MFMAs (m114). gemm feeds ONLY dmin's
// skip certificate (guard 16 covers fp8 quant error).
__global__ __launch_bounds__(512, 4) void gemm_minmax(
    const unsigned char* __restrict__ pa, const unsigned char* __restrict__ pbm,
    const float* __restrict__ pn, const float* __restrict__ ln,
    int* __restrict__ dmin)
{
  int lid = blockIdx.x;              // 512 blocks, round-robin over 8 XCDs
  int xcd = lid & 7;
  int l = lid >> 3;                  // 0..63 sequential per XCD
  int b = 2 * xcd + (l >> 5);        // 2 batches per XCD
  int p = l & 31;                    // 8 tn-panels x 4 tm-quarters
  int tn = (p & 7) * 256;
  int tmb = (p >> 3) * 512;          // 8 stripes of 64 rows each
  const unsigned char* A  = pa  + (size_t)b * N_ * D_;
  const unsigned char* Bm = pbm + (size_t)b * N_ * D_;
  // LDS union: phase 1 = Bs panel 256x256 B (64 KB); phase 2 = As dbuf
  // 2 x (64 rows x 256 B = 16 KB) in [0,32K) + pnL (512 f32) at +32K.
  __shared__ __align__(16) unsigned char smem[256 * 256];
  __shared__ float minred[8];
  unsigned char* Bs = smem;
  unsigned char* As0 = smem;
  unsigned char* As1 = smem + 16384;
  float* pnL = (float*)(smem + 32768);
  int tid = threadIdx.x, lane = tid & 63, w = tid >> 6;
  int wm = (w >> 2) * 32, wn = (w & 3) * 64;   // 2m x 4n of 32x64 wave tiles
  int l31 = lane & 31, half = lane >> 5;
  int rB = lane >> 4, cB = lane & 15;
  const int SC = 0x7F7F7F7F;         // e8m0 scale 1.0 in every byte

  // ---- phase 1: stage B panel (256 rows x 256 B) ----
  #pragma unroll
  for (int q = 0; q < 8; q++){
    int R = q * 32 + w * 4;
    int r = R + rB;
    int gc = cB ^ (r & 7);           // global-side XOR swizzle (involution)
    __builtin_amdgcn_global_load_lds(
        (const AS1 unsigned int*)(const void*)&Bm[(size_t)(tn + r) * D_ + gc * 16],
        (AS3 unsigned int*)(void*)&Bs[R * 256 + lane * 16], 16, 0, 0);
  }

  float lnj[2];
  #pragma unroll
  for (int j = 0; j < 2; j++)
    lnj[j] = ln[(size_t)b * N_ + tn + wn + j * 32 + l31];

  __syncthreads();   // Bs resident

  // ---- full-K B fragment cache: 16 x ds_read_b128 -> 64 VGPRs, read once ----
  v8i bfr[2][4];
  #pragma unroll
  for (int j = 0; j < 2; j++){
    int rb = wn + j * 32 + l31;
    #pragma unroll
    for (int kc = 0; kc < 4; kc++){
      int c0 = kc * 4 + half * 2;
      int4 lo = *(const int4*)&Bs[rb * 256 + ((c0 ^ (rb & 7)) * 16)];
      int4 hi = *(const int4*)&Bs[rb * 256 + (((c0 + 1) ^ (rb & 7)) * 16)];
      v8i t;
      t[0] = lo.x; t[1] = lo.y; t[2] = lo.z; t[3] = lo.w;
      t[4] = hi.x; t[5] = hi.y; t[6] = hi.z; t[7] = hi.w;
      bfr[j][kc] = t;
    }
  }

  __syncthreads();   // all waves done reading Bs; its LDS is now reusable

  // ---- phase 2 prologue: stage pn slice (512 f32) + A stripe 0 ----
  __builtin_amdgcn_global_load_lds(
      (const AS1 unsigned int*)(const void*)&pn[(size_t)b * N_ + tmb + tid],
      (AS3 unsigned int*)(void*)&pnL[tid], 4, 0, 0);
  #pragma unroll
  for (int q = 0; q < 2; q++){
    int R = q * 32 + w * 4;
    int r = R + rB;
    int gc = cB ^ (r & 7);
    __builtin_amdgcn_global_load_lds(
        (const AS1 unsigned int*)(const void*)&A[(size_t)(tmb + r) * D_ + gc * 16],
        (AS3 unsigned int*)(void*)&As0[R * 256 + lane * 16], 16, 0, 0);
  }

  float mind = 3.4e38f;
  int buf = 0;
  for (int step = 0; step < 8; step++){          // 8 stripes of 64 rows, full-K
    __syncthreads();   // drains As[buf]'s loads (+ pnL at step 0)
    unsigned char* Acur = buf ? As1 : As0;
    unsigned char* Anxt = buf ? As0 : As1;
    if (step < 7){
      #pragma unroll
      for (int q = 0; q < 2; q++){
        int R = q * 32 + w * 4;
        int r = R + rB;
        int gc = cB ^ (r & 7);
        __builtin_amdgcn_global_load_lds(
            (const AS1 unsigned int*)(const void*)&A[(size_t)(tmb + (step + 1) * 64 + r) * D_ + gc * 16],
            (AS3 unsigned int*)(void*)&Anxt[R * 256 + lane * 16], 16, 0, 0);
      }
    }
    f16v acc[2];
    acc[0] = (f16v)0.f; acc[1] = (f16v)0.f;

    int ra = wm + l31;               // row within the 64-row stripe
    #pragma unroll
    for (int kc = 0; kc < 4; kc++){              // k = kc*64 .. +64
      int c0 = kc * 4 + half * 2;
      int4 lo = *(const int4*)&Acur[ra * 256 + ((c0 ^ (ra & 7)) * 16)];
      int4 hi = *(const int4*)&Acur[ra * 256 + (((c0 + 1) ^ (ra & 7)) * 16)];
      v8i af;
      af[0] = lo.x; af[1] = lo.y; af[2] = lo.z; af[3] = lo.w;
      af[4] = hi.x; af[5] = hi.y; af[6] = hi.z; af[7] = hi.w;
      #pragma unroll
      for (int j = 0; j < 2; j++)
        acc[j] = __builtin_amdgcn_mfma_scale_f32_32x32x64_f8f6f4(
            af, bfr[j][kc], acc[j], 0, 0, 0, SC, 0, SC);
    }

    // epilogue: C/D col = lane&31, row = (reg&3)+8*(reg>>2)+4*half; pn via LDS
    // (broadcast reads, 2 addrs/wave). Split in reg-halves to cap transients.
    int prow0 = step * 64 + wm + half * 4;
    #pragma unroll
    for (int h = 0; h < 2; h++){
      float4 p0 = *(const float4*)&pnL[prow0 + h * 16];
      float4 p1 = *(const float4*)&pnL[prow0 + h * 16 + 8];
      float pv[8] = {p0.x, p0.y, p0.z, p0.w, p1.x, p1.y, p1.z, p1.w};
      #pragma unroll
      for (int j = 0; j < 2; j++){
        #pragma unroll
        for (int r8 = 0; r8 < 8; r8++){
          float v = pv[r8] + lnj[j] - 2.f * acc[j][h * 8 + r8];
          mind = fminf(mind, v);
        }
      }
    }
    buf ^= 1;
  }

  #pragma unroll
  for (int off = 32; off >= 1; off >>= 1) mind = fminf(mind, __shfl_xor(mind, off));
  if (lane == 0) minred[w] = mind;
  __syncthreads();
  if (tid == 0){
    float m = minred[0];
    #pragma unroll
    for (int q = 1; q < 8; q++) m = fminf(m, minred[q]);
    atomicMin(&dmin[b], __float_as_int(fmaxf(m, 0.f)));
  }
}

// Merged tail: (1) exact fallback for the 6 negative exp-factors (each skipped
// when provably negligible: B*N^2*dmax*e^{ef*dmin}/EPS < 1e-3 iff
// ef*(dmin-16) < -55; guard 16 covers fp8 dot quantization error, |err|<~8
// at 5-sigma over 4M pairs; gating monotone — if ef=-0.25 skips, all skip);
// (2) the ef=0 term. FAST PATH (all skipped -> cost == currency == 1 exactly):
// alpha = 1/2048 exactly, bw = 1, term = sum|p|^2 + sum|l|^2 - (sum p).(sum l)/1024
// from prep's fp32 partials. SLOW PATH (dead here): exact from fp32 originals.
__global__ __launch_bounds__(256) void tail(
    const float* __restrict__ preds, const float* __restrict__ labels,
    const float* __restrict__ pn, const float* __restrict__ ln,
    float* __restrict__ cost, float* __restrict__ currency,
    const int* __restrict__ dmin, const float* __restrict__ Ppart,
    const float* __restrict__ npart, float* __restrict__ out)
{
  const float EF[6] = {-256.f, -64.f, -16.f, -4.f, -1.f, -0.25f};
  int b = blockIdx.x, tid = threadIdx.x;
  float dm = __int_as_float(dmin[b]);
  __shared__ float red[256];

  if (-0.25f * (dm - 16.f) < -55.f){
    // ---- fast path: all 6 negative iterations certified negligible ----
    float Pc = 0.f, Lc = 0.f;
    for (int k = 0; k < 128; k++){
      Pc += Ppart[((size_t)b * 128 + k) * 256 + tid];
      Lc += Ppart[((size_t)(2048 + b * 128 + k)) * 256 + tid];
    }
    float np = (tid < 128) ? npart[b * 128 + tid] : 0.f;
    float nl = (tid < 128) ? npart[2048 + b * 128 + tid] : 0.f;
    float Spn = blockReduceSum(np, red);
    float Sln = blockReduceSum(nl, red);
    float dot = blockReduceSum(Pc * Lc, red);
    if (tid == 0) atomicAdd(out, Spn + Sln - dot * (1.f / 1024.f));
    return;
  }

  // ---- slow exact path from fp32 originals (not expected to execute) ----
  __shared__ float alpha_l[N_];
  __shared__ float prow[D_];
  const float* A  = preds  + (size_t)b * N_ * D_;
  const float* Bm = labels + (size_t)b * N_ * D_;
  const float* pnb = pn + (size_t)b * N_;
  const float* lnb = ln + (size_t)b * N_;
  float* costb = cost + (size_t)b * N_;
  float* curb  = currency + (size_t)b * N_;
  for (int it = 0; it < 6; it++){
    float ef = EF[it];
    if (ef * (dm - 16.f) < -55.f) continue;
    float cost_c[8], colsum_c[8], bw_c[8], costnew_c[8];
    #pragma unroll
    for (int j = 0; j < 8; j++){ cost_c[j] = costb[j*256+tid]; colsum_c[j] = 0.f; }
    for (int r = 0; r < N_; r++){
      prow[tid] = A[(size_t)r * D_ + tid];
      __syncthreads();
      float s_c[8], rs = 0.f;
      for (int j = 0; j < 8; j++){
        int m = j*256+tid; float dot = 0.f;
        for (int k = 0; k < D_; k++) dot += prow[k] * Bm[(size_t)m * D_ + k];
        float d = pnb[r] + lnb[m] - 2.f*dot;
        float s = __expf(ef * d) * cost_c[j];
        s_c[j] = s; rs += s;
      }
      float tot = blockReduceSum(rs, red);
      float a = curb[r] / (tot + EPS_);
      if (tid == 0) alpha_l[r] = a;
      #pragma unroll
      for (int j = 0; j < 8; j++) colsum_c[j] += s_c[j] * a;
      __syncthreads();
    }
    #pragma unroll
    for (int j = 0; j < 8; j++){
      float cs = colsum_c[j];
      float bw = fminf(cost_c[j] / (cs + EPS_), 1.f);
      bw_c[j] = bw; costnew_c[j] = fmaxf(cost_c[j] - bw*cs, 0.f);
    }
    float contrib = 0.f;
    for (int r = 0; r < N_; r++){
      prow[tid] = A[(size_t)r * D_ + tid];
      __syncthreads();
      float a = alpha_l[r], rbs = 0.f;
      for (int j = 0; j < 8; j++){
        int m = j*256+tid; float dot = 0.f;
        for (int k = 0; k < D_; k++) dot += prow[k] * Bm[(size_t)m * D_ + k];
        float d = pnb[r] + lnb[m] - 2.f*dot;
        float bid = __expf(ef * d) * cost_c[j] * a * bw_c[j];
        rbs += bid; contrib += bid * d;
      }
      float tot = blockReduceSum(rbs, red);
      if (tid == 0) curb[r] = fmaxf(curb[r] - tot, 0.f);
      __syncthreads();
    }
    #pragma unroll
    for (int j = 0; j < 8; j++) costb[j*256+tid] = costnew_c[j];
    float ctot = blockReduceSum(contrib, red);
    if (tid == 0) atomicAdd(out, ctot);
    __syncthreads();
  }
  // ef=0 closed form with the general state (exact):
  float s = 0.f;
  #pragma unroll
  for (int j = 0; j < 8; j++) s += costb[j*256+tid];
  float Sc = blockReduceSum(s, red);
  float sa = 0.f, spn = 0.f;
  #pragma unroll
  for (int j = 0; j < 8; j++){
    int i = j*256+tid;
    float a = curb[i] / (Sc + EPS_);
    alpha_l[i] = a; sa += a; spn += a * pnb[i];
  }
  float Sa  = blockReduceSum(sa, red);
  float Spn = blockReduceSum(spn, red);
  float Pc = 0.f;
  for (int r = 0; r < N_; r++)
    Pc += alpha_l[r] * A[(size_t)r * D_ + tid];
  __syncthreads();
  float sv = 0.f, sln = 0.f;
  #pragma unroll
  for (int j = 0; j < 8; j++){
    int i = j*256+tid;
    float c = costb[i];
    float bw = fminf(c / (c * Sa + EPS_), 1.f);
    float vv = c * bw;
    alpha_l[i] = vv; sv += vv; sln += vv * lnb[i];
  }
  float Sv  = blockReduceSum(sv, red);
  float Sln = blockReduceSum(sln, red);
  float Lc = 0.f;
  for (int m = 0; m < N_; m++)
    Lc += alpha_l[m] * Bm[(size_t)m * D_ + tid];
  float dot = blockReduceSum(Pc * Lc, red);
  if (tid == 0) atomicAdd(out, Spn * Sv + Sa * Sln - 2.f * dot);
}

extern "C" void kernel_launch(void* const* d_in, const int* in_sizes, int n_in,
                              void* d_out, int out_size, void* d_ws, size_t ws_size,
                              hipStream_t stream)
{
  const float* preds  = (const float*)d_in[0];
  const float* labels = (const float*)d_in[1];
  float* out = (float*)d_out;
  char* ws = (char*)d_ws;
  const size_t BN = (size_t)B_ * N_;
  size_t off = 0;
  float* cost     = (float*)(ws + off); off += BN * 4;
  float* currency = (float*)(ws + off); off += BN * 4;
  float* pn       = (float*)(ws + off); off += BN * 4;
  float* ln       = (float*)(ws + off); off += BN * 4;
  int*   dmin     = (int*)(ws + off);   off += 256;
  float* npart    = (float*)(ws + off); off += (size_t)2 * 2048 * 4;
  float* Ppart    = (float*)(ws + off); off += (size_t)2 * 2048 * 256 * 4;
  unsigned char* pa8 = (unsigned char*)(ws + off); off += BN * D_;
  unsigned char* pb8 = (unsigned char*)(ws + off); off += BN * D_;

  prep_kernel<<<dim3((unsigned)(BN / 16), 2), 256, 0, stream>>>(
      preds, labels, pa8, pb8, pn, ln, cost, currency, dmin, Ppart, npart, out);
  gemm_minmax<<<dim3(512), 512, 0, stream>>>(pa8, pb8, pn, ln, dmin);
  tail<<<dim3(B_), 256, 0, stream>>>(preds, labels, pn, ln, cost, currency, dmin,
                                     Ppart, npart, out);
}

// Round 8
// 127.108 us; speedup vs baseline: 1.1155x; 1.1155x over previous
//
#include <hip/hip_runtime.h>
#include <cstdint>

#define B_ 16
#define N_ 2048
#define D_ 256
#define EPS_ 1e-9f

#define AS1 __attribute__((address_space(1)))
#define AS3 __attribute__((address_space(3)))

typedef float f4 __attribute__((ext_vector_type(4)));
typedef float f16v __attribute__((ext_vector_type(16)));
typedef int v8i __attribute__((ext_vector_type(8)));

__device__ float blockReduceSum(float x, float* red){
  int tid = threadIdx.x;
  red[tid] = x; __syncthreads();
  #pragma unroll
  for (int off = 128; off > 0; off >>= 1){
    if (tid < off) red[tid] += red[tid + off];
    __syncthreads();
  }
  float r = red[0]; __syncthreads();
  return r;
}

// fp32 norm + fp8(e4m3) conversion; 4 rows/wave, 16 rows/block (one batch/block).
// Emits race-free per-block partials Ppart/npart for tail's fast path.
// Also inits cost/currency/dmin/out (no separate memset dispatch).
__global__ __launch_bounds__(256) void prep_kernel(
    const float* __restrict__ preds, const float* __restrict__ labels,
    unsigned char* __restrict__ pa8, unsigned char* __restrict__ pb8,
    float* __restrict__ pn, float* __restrict__ ln,
    float* __restrict__ cost, float* __restrict__ currency,
    int* __restrict__ dmin, float* __restrict__ Ppart,
    float* __restrict__ npart, float* __restrict__ out){
  int s = blockIdx.y;
  int tid = threadIdx.x;
  if (s == 0){
    int i = blockIdx.x * 256 + tid;
    if (i < B_ * N_){ cost[i] = 1.f; currency[i] = 1.f; }
    if (i < B_) dmin[i] = 0x7f7fffff;  // FLT_MAX bits
    if (i == 0) out[0] = 0.f;
  }
  const float* src = s ? labels : preds;
  unsigned char* dst = s ? pb8 : pa8;
  float* norms = s ? ln : pn;
  int w = tid >> 6, lane = tid & 63;
  size_t row0 = (size_t)blockIdx.x * 16 + (size_t)w * 4;
  float4 v[4];
  #pragma unroll
  for (int q = 0; q < 4; q++)
    v[q] = ((const float4*)(src + (row0 + q) * D_))[lane];
  __shared__ f4 part[4][64];
  __shared__ float nred[4];
  f4 s4;
  s4[0] = v[0].x + v[1].x + v[2].x + v[3].x;
  s4[1] = v[0].y + v[1].y + v[2].y + v[3].y;
  s4[2] = v[0].z + v[1].z + v[2].z + v[3].z;
  s4[3] = v[0].w + v[1].w + v[2].w + v[3].w;
  float nsum = 0.f;
  #pragma unroll
  for (int q = 0; q < 4; q++){
    float sum = v[q].x*v[q].x + v[q].y*v[q].y + v[q].z*v[q].z + v[q].w*v[q].w;
    #pragma unroll
    for (int off = 32; off >= 1; off >>= 1) sum += __shfl_xor(sum, off);
    if (lane == 0){ norms[row0 + q] = sum; nsum += sum; }
    int pk = 0;
    pk = __builtin_amdgcn_cvt_pk_fp8_f32(v[q].x, v[q].y, pk, false); // bytes 0,1
    pk = __builtin_amdgcn_cvt_pk_fp8_f32(v[q].z, v[q].w, pk, true);  // bytes 2,3
    ((unsigned int*)(dst + (row0 + q) * D_))[lane] = (unsigned int)pk;
  }
  part[w][lane] = s4;
  if (lane == 0) nred[w] = nsum;
  __syncthreads();
  if (tid < 64){
    f4 t = part[0][tid];
    #pragma unroll
    for (int q = 1; q < 4; q++){
      t[0] += part[q][tid][0]; t[1] += part[q][tid][1];
      t[2] += part[q][tid][2]; t[3] += part[q][tid][3];
    }
    *(f4*)(Ppart + ((size_t)s * 2048 + blockIdx.x) * 256 + tid * 4) = t;
  }
  if (tid == 0)
    npart[s * 2048 + blockIdx.x] = nred[0] + nred[1] + nred[2] + nred[3];
}

// d[b][n][m] = pn[n] + ln[m] - 2*dot via MX-SCALED FP8 MFMA; NO stores — only
// per-batch min. Round-19: occupancy mechanism retried with the register
// budget FIXED. R7's spill bomb (VGPR cap 128 < demand ~150: bfr 64 + acc 32
// + transients; 59 MB scratch writes, gemm 50us) invalidated the test, but
// its OccupancyPercent=35% proved 2-blocks/CU residency works. Now: wave
// tile 32x32 — acc 16 VGPR, bfr[4] cache 32 VGPR, af 8, total ~95 << 128.
// Each of 8 waves owns a distinct 32-col slice (wn=w*32) so the block still
// covers tn=256. Bs stays PERMANENTLY resident (no LDS union, no WAR risk):
// LDS = Bs 64K + As dbuf 2x8K (32-row stripes, 16 steps) = exactly 80 KB ->
// 2 blocks/CU; minred aliases the dead Bs region (bfr cached before step 0,
// Bs never read after). All proven geometry verbatim: global-side XOR r&7
// 16-B-chunk swizzle, gload_lds wave-uniform-base staging, 32x32x64 MX MFMA
// scales=1.0, C/D col=lane&31 row=(reg&3)+8*(reg>>2)+4*half, XCD-major
// swizzle, 2 MB/XCD L2-resident. One block's barriers/staging/epilogue hide
// under the co-resident block's MFMAs (m114). gemm feeds ONLY dmin's skip
// certificate (guard 16 covers fp8 quant error).
__global__ __launch_bounds__(512, 4) void gemm_minmax(
    const unsigned char* __restrict__ pa, const unsigned char* __restrict__ pbm,
    const float* __restrict__ pn, const float* __restrict__ ln,
    int* __restrict__ dmin)
{
  int lid = blockIdx.x;              // 512 blocks, round-robin over 8 XCDs
  int xcd = lid & 7;
  int l = lid >> 3;                  // 0..63 sequential per XCD
  int b = 2 * xcd + (l >> 5);        // 2 batches per XCD
  int p = l & 31;                    // 8 tn-panels x 4 tm-quarters
  int tn = (p & 7) * 256;
  int tmb = (p >> 3) * 512;          // 16 stripes of 32 rows each
  const unsigned char* A  = pa  + (size_t)b * N_ * D_;
  const unsigned char* Bm = pbm + (size_t)b * N_ * D_;
  // LDS: Bs 64 KB resident | As dbuf 2 x 8 KB. Total 80 KB -> 2 blocks/CU.
  __shared__ __align__(16) unsigned char smem[81920];
  unsigned char* Bs  = smem;
  unsigned char* As0 = smem + 65536;
  unsigned char* As1 = smem + 65536 + 8192;
  int tid = threadIdx.x, lane = tid & 63, w = tid >> 6;
  int l31 = lane & 31, half = lane >> 5;
  int rB = lane >> 4, cB = lane & 15;
  const int SC = 0x7F7F7F7F;         // e8m0 scale 1.0 in every byte

  // ---- stage B panel (256 rows x 256 B) + A stripe 0 (32 rows x 256 B) ----
  #pragma unroll
  for (int q = 0; q < 8; q++){
    int R = q * 32 + w * 4;
    int r = R + rB;
    int gc = cB ^ (r & 7);           // global-side XOR swizzle (involution)
    __builtin_amdgcn_global_load_lds(
        (const AS1 unsigned int*)(const void*)&Bm[(size_t)(tn + r) * D_ + gc * 16],
        (AS3 unsigned int*)(void*)&Bs[R * 256 + lane * 16], 16, 0, 0);
  }
  {
    int r = w * 4 + rB;
    int gc = cB ^ (r & 7);
    __builtin_amdgcn_global_load_lds(
        (const AS1 unsigned int*)(const void*)&A[(size_t)(tmb + r) * D_ + gc * 16],
        (AS3 unsigned int*)(void*)&As0[(w * 4) * 256 + lane * 16], 16, 0, 0);
  }

  float lnr = ln[(size_t)b * N_ + tn + w * 32 + l31];

  __syncthreads();   // Bs + As0 resident

  // ---- per-wave full-K B fragment cache: 8 x ds_read_b128 -> 32 VGPRs ----
  v8i bfr[4];
  {
    int rb = w * 32 + l31;           // this wave's 32-col slice
    #pragma unroll
    for (int kc = 0; kc < 4; kc++){
      int c0 = kc * 4 + half * 2;
      int4 lo = *(const int4*)&Bs[rb * 256 + ((c0 ^ (rb & 7)) * 16)];
      int4 hi = *(const int4*)&Bs[rb * 256 + (((c0 + 1) ^ (rb & 7)) * 16)];
      v8i t;
      t[0] = lo.x; t[1] = lo.y; t[2] = lo.z; t[3] = lo.w;
      t[4] = hi.x; t[5] = hi.y; t[6] = hi.z; t[7] = hi.w;
      bfr[kc] = t;
    }
  }

  float mind = 3.4e38f;
  int buf = 0;
  for (int step = 0; step < 16; step++){         // 16 stripes of 32 rows, full-K
    __syncthreads();   // drains prefetch of current buffer (all waves)
    const unsigned char* Acur = buf ? As1 : As0;
    unsigned char* Anxt = buf ? As0 : As1;
    if (step < 15){
      int r = w * 4 + rB;
      int gc = cB ^ (r & 7);
      __builtin_amdgcn_global_load_lds(
          (const AS1 unsigned int*)(const void*)&A[(size_t)(tmb + (step + 1) * 32 + r) * D_ + gc * 16],
          (AS3 unsigned int*)(void*)&Anxt[(w * 4) * 256 + lane * 16], 16, 0, 0);
    }
    f16v acc = (f16v)0.f;
    int ra = l31;                    // row within the 32-row stripe
    #pragma unroll
    for (int kc = 0; kc < 4; kc++){              // k = kc*64 .. +64
      int c0 = kc * 4 + half * 2;
      int4 lo = *(const int4*)&Acur[ra * 256 + ((c0 ^ (ra & 7)) * 16)];
      int4 hi = *(const int4*)&Acur[ra * 256 + (((c0 + 1) ^ (ra & 7)) * 16)];
      v8i af;
      af[0] = lo.x; af[1] = lo.y; af[2] = lo.z; af[3] = lo.w;
      af[4] = hi.x; af[5] = hi.y; af[6] = hi.z; af[7] = hi.w;
      acc = __builtin_amdgcn_mfma_scale_f32_32x32x64_f8f6f4(
          af, bfr[kc], acc, 0, 0, 0, SC, 0, SC);
    }

    // epilogue: C/D col = lane&31, row = (reg&3)+8*(reg>>2)+4*half.
    int prow0 = (int)((size_t)0) + step * 32 + half * 4;
    #pragma unroll
    for (int h = 0; h < 2; h++){
      float4 p0 = *(const float4*)&pn[(size_t)b * N_ + tmb + prow0 + h * 16];
      float4 p1 = *(const float4*)&pn[(size_t)b * N_ + tmb + prow0 + h * 16 + 8];
      float pv[8] = {p0.x, p0.y, p0.z, p0.w, p1.x, p1.y, p1.z, p1.w};
      #pragma unroll
      for (int r8 = 0; r8 < 8; r8++){
        float v = pv[r8] + lnr - 2.f * acc[h * 8 + r8];
        mind = fminf(mind, v);
      }
    }
    buf ^= 1;
  }

  #pragma unroll
  for (int off = 32; off >= 1; off >>= 1) mind = fminf(mind, __shfl_xor(mind, off));
  // minred aliases the dead Bs region (bfr cached pre-loop; Bs never read since).
  float* minred = (float*)smem;
  if (lane == 0) minred[w] = mind;
  __syncthreads();
  if (tid == 0){
    float m = minred[0];
    #pragma unroll
    for (int q = 1; q < 8; q++) m = fminf(m, minred[q]);
    atomicMin(&dmin[b], __float_as_int(fmaxf(m, 0.f)));
  }
}

// Merged tail: (1) exact fallback for the 6 negative exp-factors (each skipped
// when provably negligible: B*N^2*dmax*e^{ef*dmin}/EPS < 1e-3 iff
// ef*(dmin-16) < -55; guard 16 covers fp8 dot quantization error, |err|<~8
// at 5-sigma over 4M pairs; gating monotone — if ef=-0.25 skips, all skip);
// (2) the ef=0 term. FAST PATH (all skipped -> cost == currency == 1 exactly):
// alpha = 1/2048 exactly, bw = 1, term = sum|p|^2 + sum|l|^2 - (sum p).(sum l)/1024
// from prep's fp32 partials. SLOW PATH (dead here): exact from fp32 originals.
__global__ __launch_bounds__(256) void tail(
    const float* __restrict__ preds, const float* __restrict__ labels,
    const float* __restrict__ pn, const float* __restrict__ ln,
    float* __restrict__ cost, float* __restrict__ currency,
    const int* __restrict__ dmin, const float* __restrict__ Ppart,
    const float* __restrict__ npart, float* __restrict__ out)
{
  const float EF[6] = {-256.f, -64.f, -16.f, -4.f, -1.f, -0.25f};
  int b = blockIdx.x, tid = threadIdx.x;
  float dm = __int_as_float(dmin[b]);
  __shared__ float red[256];

  if (-0.25f * (dm - 16.f) < -55.f){
    // ---- fast path: all 6 negative iterations certified negligible ----
    float Pc = 0.f, Lc = 0.f;
    for (int k = 0; k < 128; k++){
      Pc += Ppart[((size_t)b * 128 + k) * 256 + tid];
      Lc += Ppart[((size_t)(2048 + b * 128 + k)) * 256 + tid];
    }
    float np = (tid < 128) ? npart[b * 128 + tid] : 0.f;
    float nl = (tid < 128) ? npart[2048 + b * 128 + tid] : 0.f;
    float Spn = blockReduceSum(np, red);
    float Sln = blockReduceSum(nl, red);
    float dot = blockReduceSum(Pc * Lc, red);
    if (tid == 0) atomicAdd(out, Spn + Sln - dot * (1.f / 1024.f));
    return;
  }

  // ---- slow exact path from fp32 originals (not expected to execute) ----
  __shared__ float alpha_l[N_];
  __shared__ float prow[D_];
  const float* A  = preds  + (size_t)b * N_ * D_;
  const float* Bm = labels + (size_t)b * N_ * D_;
  const float* pnb = pn + (size_t)b * N_;
  const float* lnb = ln + (size_t)b * N_;
  float* costb = cost + (size_t)b * N_;
  float* curb  = currency + (size_t)b * N_;
  for (int it = 0; it < 6; it++){
    float ef = EF[it];
    if (ef * (dm - 16.f) < -55.f) continue;
    float cost_c[8], colsum_c[8], bw_c[8], costnew_c[8];
    #pragma unroll
    for (int j = 0; j < 8; j++){ cost_c[j] = costb[j*256+tid]; colsum_c[j] = 0.f; }
    for (int r = 0; r < N_; r++){
      prow[tid] = A[(size_t)r * D_ + tid];
      __syncthreads();
      float s_c[8], rs = 0.f;
      for (int j = 0; j < 8; j++){
        int m = j*256+tid; float dot = 0.f;
        for (int k = 0; k < D_; k++) dot += prow[k] * Bm[(size_t)m * D_ + k];
        float d = pnb[r] + lnb[m] - 2.f*dot;
        float s = __expf(ef * d) * cost_c[j];
        s_c[j] = s; rs += s;
      }
      float tot = blockReduceSum(rs, red);
      float a = curb[r] / (tot + EPS_);
      if (tid == 0) alpha_l[r] = a;
      #pragma unroll
      for (int j = 0; j < 8; j++) colsum_c[j] += s_c[j] * a;
      __syncthreads();
    }
    #pragma unroll
    for (int j = 0; j < 8; j++){
      float cs = colsum_c[j];
      float bw = fminf(cost_c[j] / (cs + EPS_), 1.f);
      bw_c[j] = bw; costnew_c[j] = fmaxf(cost_c[j] - bw*cs, 0.f);
    }
    float contrib = 0.f;
    for (int r = 0; r < N_; r++){
      prow[tid] = A[(size_t)r * D_ + tid];
      __syncthreads();
      float a = alpha_l[r], rbs = 0.f;
      for (int j = 0; j < 8; j++){
        int m = j*256+tid; float dot = 0.f;
        for (int k = 0; k < D_; k++) dot += prow[k] * Bm[(size_t)m * D_ + k];
        float d = pnb[r] + lnb[m] - 2.f*dot;
        float bid = __expf(ef * d) * cost_c[j] * a * bw_c[j];
        rbs += bid; contrib += bid * d;
      }
      float tot = blockReduceSum(rbs, red);
      if (tid == 0) curb[r] = fmaxf(curb[r] - tot, 0.f);
      __syncthreads();
    }
    #pragma unroll
    for (int j = 0; j < 8; j++) costb[j*256+tid] = costnew_c[j];
    float ctot = blockReduceSum(contrib, red);
    if (tid == 0) atomicAdd(out, ctot);
    __syncthreads();
  }
  // ef=0 closed form with the general state (exact):
  float s = 0.f;
  #pragma unroll
  for (int j = 0; j < 8; j++) s += costb[j*256+tid];
  float Sc = blockReduceSum(s, red);
  float sa = 0.f, spn = 0.f;
  #pragma unroll
  for (int j = 0; j < 8; j++){
    int i = j*256+tid;
    float a = curb[i] / (Sc + EPS_);
    alpha_l[i] = a; sa += a; spn += a * pnb[i];
  }
  float Sa  = blockReduceSum(sa, red);
  float Spn = blockReduceSum(spn, red);
  float Pc = 0.f;
  for (int r = 0; r < N_; r++)
    Pc += alpha_l[r] * A[(size_t)r * D_ + tid];
  __syncthreads();
  float sv = 0.f, sln = 0.f;
  #pragma unroll
  for (int j = 0; j < 8; j++){
    int i = j*256+tid;
    float c = costb[i];
    float bw = fminf(c / (c * Sa + EPS_), 1.f);
    float vv = c * bw;
    alpha_l[i] = vv; sv += vv; sln += vv * lnb[i];
  }
  float Sv  = blockReduceSum(sv, red);
  float Sln = blockReduceSum(sln, red);
  float Lc = 0.f;
  for (int m = 0; m < N_; m++)
    Lc += alpha_l[m] * Bm[(size_t)m * D_ + tid];
  float dot = blockReduceSum(Pc * Lc, red);
  if (tid == 0) atomicAdd(out, Spn * Sv + Sa * Sln - 2.f * dot);
}

extern "C" void kernel_launch(void* const* d_in, const int* in_sizes, int n_in,
                              void* d_out, int out_size, void* d_ws, size_t ws_size,
                              hipStream_t stream)
{
  const float* preds  = (const float*)d_in[0];
  const float* labels = (const float*)d_in[1];
  float* out = (float*)d_out;
  char* ws = (char*)d_ws;
  const size_t BN = (size_t)B_ * N_;
  size_t off = 0;
  float* cost     = (float*)(ws + off); off += BN * 4;
  float* currency = (float*)(ws + off); off += BN * 4;
  float* pn       = (float*)(ws + off); off += BN * 4;
  float* ln       = (float*)(ws + off); off += BN * 4;
  int*   dmin     = (int*)(ws + off);   off += 256;
  float* npart    = (float*)(ws + off); off += (size_t)2 * 2048 * 4;
  float* Ppart    = (float*)(ws + off); off += (size_t)2 * 2048 * 256 * 4;
  unsigned char* pa8 = (unsigned char*)(ws + off); off += BN * D_;
  unsigned char* pb8 = (unsigned char*)(ws + off); off += BN * D_;

  prep_kernel<<<dim3((unsigned)(BN / 16), 2), 256, 0, stream>>>(
      preds, labels, pa8, pb8, pn, ln, cost, currency, dmin, Ppart, npart, out);
  gemm_minmax<<<dim3(512), 512, 0, stream>>>(pa8, pb8, pn, ln, dmin);
  tail<<<dim3(B_), 256, 0, stream>>>(preds, labels, pn, ln, cost, currency, dmin,
                                     Ppart, npart, out);
}